// Round 1
// baseline (955.967 us; speedup 1.0000x reference)
//
#include <hip/hip_runtime.h>

// ---------------------------------------------------------------------------
// GCN stack, one workgroup per batch element.
//   B=4096 N=128 F=8 E=8 U=128 H=6 V=42
// LDS: sAdj (adj[b] bf16, loaded once, reused 6x), sX (X, [node][unit]),
//      sY (Y^T, [unit][node]).  Stride 136 (=68 dwords) kills 2^k bank alias
//      and keeps 16B alignment for ds_read_b128.
// GEMM1: Y    = relu(X @ W_h[l] + b_h[l])   (A=sX, B=Wt from ws, out->sY as Y^T)
// GEMM2: X'^T = Y^T @ adj^T                  (A=sY, B=sAdj rows,  out->sX)
// Both GEMMs: all LDS reads contiguous b128, all writes contiguous b64.
// ---------------------------------------------------------------------------

#define SP 136

typedef __bf16 bf16x8 __attribute__((ext_vector_type(8)));
typedef float  f32x4  __attribute__((ext_vector_type(4)));

__device__ __forceinline__ unsigned short f2bf(float f) {
    union { float f; unsigned u; } v; v.f = f;
    // round-to-nearest-even (bias-free: mandatory for the positive-sum chain)
    unsigned r = (v.u + 0x7FFFu + ((v.u >> 16) & 1u)) >> 16;
    return (unsigned short)r;
}
__device__ __forceinline__ float bf2f(unsigned short h) {
    union { unsigned u; float f; } v; v.u = ((unsigned)h) << 16;
    return v.f;
}
__device__ __forceinline__ f32x4 mfma16(bf16x8 a, bf16x8 b, f32x4 c) {
    return __builtin_amdgcn_mfma_f32_16x16x32_bf16(a, b, c, 0, 0, 0);
}

// ---- prep: transpose weights to bf16 in workspace -------------------------
// wt_in : [128 out][32 in]  (in 16..31 zero-padded)      8192 B
// wt_h  : [6][128 out][128 in]                          196608 B
__global__ void gcn_prep(const float* __restrict__ W_in,
                         const float* __restrict__ W_h,
                         unsigned short* __restrict__ wt_in,
                         unsigned short* __restrict__ wt_h) {
    int idx = blockIdx.x * 256 + threadIdx.x;
    if (idx < 4096) {
        int o = idx >> 5, i = idx & 31;
        wt_in[idx] = (i < 16) ? f2bf(W_in[i * 128 + o]) : (unsigned short)0;
    } else {
        int j = idx - 4096;
        if (j < 98304) {
            int l = j >> 14, r = j & 16383, o = r >> 7, i = r & 127;
            wt_h[j] = f2bf(W_h[l * 16384 + i * 128 + o]);
        }
    }
}

__global__ __launch_bounds__(512, 2) void gcn_main(
    const int* __restrict__ pdg, const float* __restrict__ feat,
    const float* __restrict__ adj, const float* __restrict__ mask,
    const float* __restrict__ emb, const float* __restrict__ b_in,
    const float* __restrict__ b_h, const float* __restrict__ W_out,
    const float* __restrict__ b_out,
    const unsigned short* __restrict__ wt_in,
    const unsigned short* __restrict__ wt_h,
    float* __restrict__ out) {

    __shared__ unsigned short sAdj[128 * SP];
    __shared__ unsigned short sX[128 * SP];
    __shared__ unsigned short sY[128 * SP];
    __shared__ float red[16];

    const int b    = blockIdx.x;
    const int tid  = threadIdx.x;
    const int lane = tid & 63;
    const int wave = tid >> 6;
    const int q    = lane >> 4;   // k-chunk / row-quad
    const int c    = lane & 15;   // fragment row/col within 16
    const int wm   = wave & 3;    // m-tile: 32*wm
    const int wn   = wave >> 2;   // n-tile: 64*wn

    // ---- stage adj[b] -> sAdj (fp32 -> bf16, RNE) ----
    {
        const float4* src = (const float4*)(adj + (size_t)b * 16384);
        #pragma unroll
        for (int i = 0; i < 8; ++i) {
            int idx = i * 512 + tid;          // float4 index
            float4 v = src[idx];
            int row = idx >> 5, col = (idx & 31) << 2;
            union { unsigned short h[4]; uint2 u; } w;
            w.h[0] = f2bf(v.x); w.h[1] = f2bf(v.y);
            w.h[2] = f2bf(v.z); w.h[3] = f2bf(v.w);
            *(uint2*)&sAdj[row * SP + col] = w.u;
        }
    }
    // ---- stage X0 = [feat | emb | 0] as [node][32] bf16 into sY region ----
    {
        int node = tid >> 2, part = tid & 3;
        if (part == 0) {
            const float* f = feat + ((size_t)b * 128 + node) * 8;
            union { unsigned short h[8]; uint4 u; } w;
            #pragma unroll
            for (int i = 0; i < 8; ++i) w.h[i] = f2bf(f[i]);
            *(uint4*)&sY[node * 32] = w.u;
        } else if (part == 1) {
            const float* e = emb + pdg[b * 128 + node] * 8;
            union { unsigned short h[8]; uint4 u; } w;
            #pragma unroll
            for (int i = 0; i < 8; ++i) w.h[i] = f2bf(e[i]);
            *(uint4*)&sY[node * 32 + 8] = w.u;
        } else {
            uint4 z; z.x = z.y = z.z = z.w = 0u;
            *(uint4*)&sY[node * 32 + ((part == 2) ? 16 : 24)] = z;
        }
    }
    __syncthreads();

    // ---- input layer: X1^T = Wt_in @ X0^T (K=32, 1 step); X1 -> sX ----
    {
        f32x4 acc[2][4];
        #pragma unroll
        for (int rt = 0; rt < 2; ++rt)
            #pragma unroll
            for (int ct = 0; ct < 4; ++ct) acc[rt][ct] = (f32x4){0.f, 0.f, 0.f, 0.f};
        bf16x8 afr[2], bfr[4];
        #pragma unroll
        for (int rt = 0; rt < 2; ++rt)
            afr[rt] = *(const bf16x8*)&wt_in[(wm * 32 + rt * 16 + c) * 32 + q * 8];
        #pragma unroll
        for (int ct = 0; ct < 4; ++ct)
            bfr[ct] = *(const bf16x8*)&sY[(wn * 64 + ct * 16 + c) * 32 + q * 8];
        #pragma unroll
        for (int rt = 0; rt < 2; ++rt)
            #pragma unroll
            for (int ct = 0; ct < 4; ++ct)
                acc[rt][ct] = mfma16(afr[rt], bfr[ct], acc[rt][ct]);
        #pragma unroll
        for (int rt = 0; rt < 2; ++rt) {
            int u0 = wm * 32 + rt * 16 + q * 4;      // 4 consecutive units
            float4 bi = *(const float4*)&b_in[u0];
            #pragma unroll
            for (int ct = 0; ct < 4; ++ct) {
                int node = wn * 64 + ct * 16 + c;
                union { unsigned short h[4]; uint2 u; } w;
                w.h[0] = f2bf(acc[rt][ct][0] + bi.x);
                w.h[1] = f2bf(acc[rt][ct][1] + bi.y);
                w.h[2] = f2bf(acc[rt][ct][2] + bi.z);
                w.h[3] = f2bf(acc[rt][ct][3] + bi.w);
                *(uint2*)&sX[node * SP + u0] = w.u;
            }
        }
    }
    __syncthreads();

    // ---- 6 hidden layers ----
    #pragma unroll 1
    for (int l = 0; l < 6; ++l) {
        const unsigned short* wt = wt_h + l * 16384;   // Wt[l]: [out][in] bf16
        // GEMM1: Y = relu(X @ W + b) ; store Y^T in sY[unit][node]
        {
            f32x4 acc[2][4];
            #pragma unroll
            for (int rt = 0; rt < 2; ++rt)
                #pragma unroll
                for (int ct = 0; ct < 4; ++ct) acc[rt][ct] = (f32x4){0.f, 0.f, 0.f, 0.f};
            #pragma unroll
            for (int ks = 0; ks < 4; ++ks) {
                bf16x8 a0 = *(const bf16x8*)&sX[(wm * 32 +  0 + c) * SP + ks * 32 + q * 8];
                bf16x8 a1 = *(const bf16x8*)&sX[(wm * 32 + 16 + c) * SP + ks * 32 + q * 8];
                bf16x8 b0 = *(const bf16x8*)&wt[(wn * 64 +  0 + c) * 128 + ks * 32 + q * 8];
                bf16x8 b1 = *(const bf16x8*)&wt[(wn * 64 + 16 + c) * 128 + ks * 32 + q * 8];
                bf16x8 b2 = *(const bf16x8*)&wt[(wn * 64 + 32 + c) * 128 + ks * 32 + q * 8];
                bf16x8 b3 = *(const bf16x8*)&wt[(wn * 64 + 48 + c) * 128 + ks * 32 + q * 8];
                acc[0][0] = mfma16(a0, b0, acc[0][0]);
                acc[0][1] = mfma16(a0, b1, acc[0][1]);
                acc[0][2] = mfma16(a0, b2, acc[0][2]);
                acc[0][3] = mfma16(a0, b3, acc[0][3]);
                acc[1][0] = mfma16(a1, b0, acc[1][0]);
                acc[1][1] = mfma16(a1, b1, acc[1][1]);
                acc[1][2] = mfma16(a1, b2, acc[1][2]);
                acc[1][3] = mfma16(a1, b3, acc[1][3]);
            }
            #pragma unroll
            for (int ct = 0; ct < 4; ++ct) {
                int u = wn * 64 + ct * 16 + c;
                float bias = b_h[l * 128 + u];
                #pragma unroll
                for (int rt = 0; rt < 2; ++rt) {
                    int n0 = wm * 32 + rt * 16 + q * 4;  // 4 consecutive nodes
                    union { unsigned short h[4]; uint2 u2; } w;
                    #pragma unroll
                    for (int j = 0; j < 4; ++j)
                        w.h[j] = f2bf(fmaxf(acc[rt][ct][j] + bias, 0.f));
                    *(uint2*)&sY[u * SP + n0] = w.u2;
                }
            }
        }
        __syncthreads();
        // GEMM2: X'^T = Y^T @ adj^T ; store X' in sX[node][unit]
        {
            f32x4 acc[2][4];
            #pragma unroll
            for (int rt = 0; rt < 2; ++rt)
                #pragma unroll
                for (int ct = 0; ct < 4; ++ct) acc[rt][ct] = (f32x4){0.f, 0.f, 0.f, 0.f};
            #pragma unroll
            for (int ks = 0; ks < 4; ++ks) {
                bf16x8 a0 = *(const bf16x8*)&sY[(wm * 32 +  0 + c) * SP + ks * 32 + q * 8];
                bf16x8 a1 = *(const bf16x8*)&sY[(wm * 32 + 16 + c) * SP + ks * 32 + q * 8];
                bf16x8 b0 = *(const bf16x8*)&sAdj[(wn * 64 +  0 + c) * SP + ks * 32 + q * 8];
                bf16x8 b1 = *(const bf16x8*)&sAdj[(wn * 64 + 16 + c) * SP + ks * 32 + q * 8];
                bf16x8 b2 = *(const bf16x8*)&sAdj[(wn * 64 + 32 + c) * SP + ks * 32 + q * 8];
                bf16x8 b3 = *(const bf16x8*)&sAdj[(wn * 64 + 48 + c) * SP + ks * 32 + q * 8];
                acc[0][0] = mfma16(a0, b0, acc[0][0]);
                acc[0][1] = mfma16(a0, b1, acc[0][1]);
                acc[0][2] = mfma16(a0, b2, acc[0][2]);
                acc[0][3] = mfma16(a0, b3, acc[0][3]);
                acc[1][0] = mfma16(a1, b0, acc[1][0]);
                acc[1][1] = mfma16(a1, b1, acc[1][1]);
                acc[1][2] = mfma16(a1, b2, acc[1][2]);
                acc[1][3] = mfma16(a1, b3, acc[1][3]);
            }
            #pragma unroll
            for (int ct = 0; ct < 4; ++ct) {
                int node = wn * 64 + ct * 16 + c;
                #pragma unroll
                for (int rt = 0; rt < 2; ++rt) {
                    int u0 = wm * 32 + rt * 16 + q * 4;  // 4 consecutive units
                    union { unsigned short h[4]; uint2 u2; } w;
                    #pragma unroll
                    for (int j = 0; j < 4; ++j) w.h[j] = f2bf(acc[rt][ct][j]);
                    *(uint2*)&sX[node * SP + u0] = w.u2;
                }
            }
        }
        __syncthreads();
    }

    // ---- epilogue: masked mean pool + W_out dot ----
    {
        int node = tid >> 2, seg = tid & 3;
        const unsigned short* xr = &sX[node * SP + seg * 32];
        const float* wo = W_out + seg * 32;
        float part = 0.f;
        #pragma unroll
        for (int u = 0; u < 32; ++u) part += bf2f(xr[u]) * wo[u];
        float mv = mask[b * 128 + node];
        part *= mv;
        float msum = (seg == 0) ? mv : 0.f;
        #pragma unroll
        for (int off = 32; off > 0; off >>= 1) {
            part += __shfl_down(part, off);
            msum += __shfl_down(msum, off);
        }
        if (lane == 0) { red[wave] = part; red[8 + wave] = msum; }
        __syncthreads();
        if (tid == 0) {
            float s = 0.f, ms = 0.f;
            #pragma unroll
            for (int i = 0; i < 8; ++i) { s += red[i]; ms += red[8 + i]; }
            out[b] = s / fmaxf(ms, 1.f) + b_out[0];
        }
    }
}

extern "C" void kernel_launch(void* const* d_in, const int* in_sizes, int n_in,
                              void* d_out, int out_size, void* d_ws, size_t ws_size,
                              hipStream_t stream) {
    const int*   pdg   = (const int*)d_in[0];
    const float* feat  = (const float*)d_in[1];
    const float* adj   = (const float*)d_in[2];
    const float* mask  = (const float*)d_in[3];
    const float* emb   = (const float*)d_in[4];
    const float* W_in  = (const float*)d_in[5];
    const float* b_in  = (const float*)d_in[6];
    const float* W_h   = (const float*)d_in[7];
    const float* b_h   = (const float*)d_in[8];
    const float* W_out = (const float*)d_in[9];
    const float* b_out = (const float*)d_in[10];

    unsigned short* wt_in = (unsigned short*)d_ws;          // 128*32 bf16
    unsigned short* wt_h  = wt_in + 4096;                   // 6*128*128 bf16

    gcn_prep<<<400, 256, 0, stream>>>(W_in, W_h, wt_in, wt_h);
    gcn_main<<<4096, 512, 0, stream>>>(pdg, feat, adj, mask, emb, b_in, b_h,
                                       W_out, b_out, wt_in, wt_h, (float*)d_out);
}

// Round 2
// 625.793 us; speedup vs baseline: 1.5276x; 1.5276x over previous
//
#include <hip/hip_runtime.h>

// ---------------------------------------------------------------------------
// GCN stack, one workgroup (512 thr) per batch element, 2 WG/CU.
//   B=4096 N=128 U=128 H=6
// Key structure vs round 1:
//  - adj B-fragments live in REGISTERS for the whole kernel (32 VGPR):
//    adj is the identical MFMA B-operand of all 6 aggregation GEMMs, so it
//    never touches LDS. This removes the 34 KB sAdj buffer -> 64 KB LDS/WG
//    -> 2 WG/CU, and removes 128 KB/GEMM of LDS B-traffic.
//  - XOR-swizzled LDS layout (chunk' = chunk16B ^ (row&7)), zero padding:
//    frag reads hit each 4-bank group with exactly 8 lanes/wave (balanced),
//    epilogue 8B writes likewise. Replaces the SP=136 pad whose dword
//    stride 68 = 4 (mod 32) caused 8-way conflicts (3.9e7 conflict cycles).
//  - hardware RNE bf16 converts (v_cvt_pk_bf16_f32) via convertvector.
// Wave tiling (Wm=2, Wn=4): each wave computes 64 rows x 32 cols,
//    acc[4][2] f32x4 = 32 VGPR, A-traffic 64 KB/GEMM total.
// GEMM1: Y^T  = relu(X @ W_h[l] + b)^T   A=sX rows,  B=wt_h (global, L1-hot)
// GEMM2: X'^T = Y^T @ adj^T              A=sY rows,  B=adjB registers
// ---------------------------------------------------------------------------

typedef __bf16  bf16x8 __attribute__((ext_vector_type(8)));
typedef __bf16  bf16x4 __attribute__((ext_vector_type(4)));
typedef float   f32x4  __attribute__((ext_vector_type(4)));
typedef float   f32x8  __attribute__((ext_vector_type(8)));

__device__ __forceinline__ f32x4 mfma16(bf16x8 a, bf16x8 b, f32x4 c) {
    return __builtin_amdgcn_mfma_f32_16x16x32_bf16(a, b, c, 0, 0, 0);
}
// swizzled LDS index (shorts). row in [0,128), col in [0,128).
// 16B chunk swizzle: chunk' = chunk ^ (row & 7); conflict-balanced for both
// the (c,q) frag-read pattern and the (q*4) half-chunk epilogue writes.
__device__ __forceinline__ int sidx(int row, int col) {
    return (row << 7) + ((((col >> 3) ^ (row & 7)) << 3) | (col & 7));
}
__device__ __forceinline__ bf16x8 cvt8(float4 lo, float4 hi) {
    f32x8 f; f[0]=lo.x; f[1]=lo.y; f[2]=lo.z; f[3]=lo.w;
             f[4]=hi.x; f[5]=hi.y; f[6]=hi.z; f[7]=hi.w;
    return __builtin_convertvector(f, bf16x8);   // RNE, v_cvt_pk_bf16_f32
}
__device__ __forceinline__ bf16x4 cvt4(f32x4 v) {
    return __builtin_convertvector(v, bf16x4);
}

// ---- prep: transpose weights to bf16 in workspace -------------------------
// wt_in : [128 out][32 in] (in 16..31 zero)   8 KB
// wt_h  : [6][128 out][128 in]              192 KB
__global__ void gcn_prep(const float* __restrict__ W_in,
                         const float* __restrict__ W_h,
                         __bf16* __restrict__ wt_in,
                         __bf16* __restrict__ wt_h) {
    int idx = blockIdx.x * 256 + threadIdx.x;
    if (idx < 4096) {
        int o = idx >> 5, i = idx & 31;
        wt_in[idx] = (i < 16) ? (__bf16)W_in[i * 128 + o] : (__bf16)0.f;
    } else {
        int j = idx - 4096;
        if (j < 98304) {
            int l = j >> 14, r = j & 16383, o = r >> 7, i = r & 127;
            wt_h[j] = (__bf16)W_h[l * 16384 + i * 128 + o];
        }
    }
}

__global__ __launch_bounds__(512, 4) void gcn_main(
    const int* __restrict__ pdg, const float* __restrict__ feat,
    const float* __restrict__ adj, const float* __restrict__ mask,
    const float* __restrict__ emb, const float* __restrict__ b_in,
    const float* __restrict__ b_h, const float* __restrict__ W_out,
    const float* __restrict__ b_out,
    const __bf16* __restrict__ wt_in, const __bf16* __restrict__ wt_h,
    float* __restrict__ out) {

    __shared__ __attribute__((aligned(16))) __bf16 sX[128 * 128];  // 32 KB
    __shared__ __attribute__((aligned(16))) __bf16 sY[128 * 128];  // 32 KB
    __shared__ float red[16];

    const int b    = blockIdx.x;
    const int tid  = threadIdx.x;
    const int lane = tid & 63;
    const int wave = tid >> 6;
    const int q    = lane >> 4;   // k-chunk quad / row-quad of C
    const int c    = lane & 15;   // fragment row/col within 16
    const int wm   = wave >> 2;   // m-tile base: 64*wm   (2 groups)
    const int wn   = wave & 3;    // n-tile base: 32*wn   (4 groups)

    // ---- adj B-fragments -> registers (fp32 -> bf16 RNE), held all kernel --
    // lane (q,c), frag [ct][ks] = adj[wn*32+ct*16+c][ks*32+q*8 .. +7]
    bf16x8 adjB[2][4];
    {
        const float* ap = adj + (size_t)b * 16384;
        #pragma unroll
        for (int ct = 0; ct < 2; ++ct) {
            const float* rp = ap + (wn * 32 + ct * 16 + c) * 128 + q * 8;
            #pragma unroll
            for (int ks = 0; ks < 4; ++ks) {
                const float4* p = (const float4*)(rp + ks * 32);
                adjB[ct][ks] = cvt8(p[0], p[1]);
            }
        }
    }

    // ---- stage X0 = [feat | emb | 0] as [node][32] into sY (swizzled) ----
    {
        int node = tid >> 2, part = tid & 3;
        bf16x8 v;
        if (part == 0) {
            const float4* f = (const float4*)(feat + ((size_t)b * 128 + node) * 8);
            v = cvt8(f[0], f[1]);
        } else if (part == 1) {
            const float4* e = (const float4*)(emb + pdg[b * 128 + node] * 8);
            v = cvt8(e[0], e[1]);
        } else {
            #pragma unroll
            for (int i = 0; i < 8; ++i) v[i] = (__bf16)0.f;
        }
        *(bf16x8*)&sY[sidx(node, part * 8)] = v;
    }
    __syncthreads();

    // ---- input layer: X1^T = Wt_in @ X0^T (K=32); X1 -> sX [node][unit] ---
    {
        f32x4 acc[4][2];
        #pragma unroll
        for (int rt = 0; rt < 4; ++rt)
            #pragma unroll
            for (int ct = 0; ct < 2; ++ct) acc[rt][ct] = (f32x4){0.f,0.f,0.f,0.f};
        bf16x8 afr[4], bfr[2];
        #pragma unroll
        for (int rt = 0; rt < 4; ++rt)
            afr[rt] = *(const bf16x8*)&wt_in[(wm * 64 + rt * 16 + c) * 32 + q * 8];
        #pragma unroll
        for (int ct = 0; ct < 2; ++ct)
            bfr[ct] = *(const bf16x8*)&sY[sidx(wn * 32 + ct * 16 + c, q * 8)];
        #pragma unroll
        for (int rt = 0; rt < 4; ++rt)
            #pragma unroll
            for (int ct = 0; ct < 2; ++ct)
                acc[rt][ct] = mfma16(afr[rt], bfr[ct], acc[rt][ct]);
        #pragma unroll
        for (int ct = 0; ct < 2; ++ct) {
            int node = wn * 32 + ct * 16 + c;
            #pragma unroll
            for (int rt = 0; rt < 4; ++rt) {
                int u0 = wm * 64 + rt * 16 + q * 4;     // 4 consecutive units
                float4 bi = *(const float4*)&b_in[u0];
                f32x4 v;
                v[0] = acc[rt][ct][0] + bi.x; v[1] = acc[rt][ct][1] + bi.y;
                v[2] = acc[rt][ct][2] + bi.z; v[3] = acc[rt][ct][3] + bi.w;
                *(bf16x4*)&sX[sidx(node, u0)] = cvt4(v);
            }
        }
    }
    __syncthreads();

    // ---- 6 hidden layers ----
    #pragma unroll 1
    for (int l = 0; l < 6; ++l) {
        const __bf16* wt = wt_h + l * 16384;   // [out][in] bf16
        // GEMM1: Y = relu(X @ W + b); store Y^T -> sY[unit][node]
        {
            f32x4 acc[4][2];
            #pragma unroll
            for (int rt = 0; rt < 4; ++rt)
                #pragma unroll
                for (int ct = 0; ct < 2; ++ct) acc[rt][ct] = (f32x4){0.f,0.f,0.f,0.f};
            #pragma unroll
            for (int ks = 0; ks < 4; ++ks) {
                bf16x8 a0 = *(const bf16x8*)&sX[sidx(wm * 64 +  0 + c, ks * 32 + q * 8)];
                bf16x8 a1 = *(const bf16x8*)&sX[sidx(wm * 64 + 16 + c, ks * 32 + q * 8)];
                bf16x8 a2 = *(const bf16x8*)&sX[sidx(wm * 64 + 32 + c, ks * 32 + q * 8)];
                bf16x8 a3 = *(const bf16x8*)&sX[sidx(wm * 64 + 48 + c, ks * 32 + q * 8)];
                bf16x8 w0 = *(const bf16x8*)&wt[(wn * 32 +  0 + c) * 128 + ks * 32 + q * 8];
                bf16x8 w1 = *(const bf16x8*)&wt[(wn * 32 + 16 + c) * 128 + ks * 32 + q * 8];
                acc[0][0] = mfma16(a0, w0, acc[0][0]);
                acc[1][0] = mfma16(a1, w0, acc[1][0]);
                acc[2][0] = mfma16(a2, w0, acc[2][0]);
                acc[3][0] = mfma16(a3, w0, acc[3][0]);
                acc[0][1] = mfma16(a0, w1, acc[0][1]);
                acc[1][1] = mfma16(a1, w1, acc[1][1]);
                acc[2][1] = mfma16(a2, w1, acc[2][1]);
                acc[3][1] = mfma16(a3, w1, acc[3][1]);
            }
            #pragma unroll
            for (int ct = 0; ct < 2; ++ct) {
                int u = wn * 32 + ct * 16 + c;
                float bias = b_h[l * 128 + u];
                #pragma unroll
                for (int rt = 0; rt < 4; ++rt) {
                    int n0 = wm * 64 + rt * 16 + q * 4;  // 4 consecutive nodes
                    f32x4 v;
                    #pragma unroll
                    for (int j = 0; j < 4; ++j) v[j] = fmaxf(acc[rt][ct][j] + bias, 0.f);
                    *(bf16x4*)&sY[sidx(u, n0)] = cvt4(v);
                }
            }
        }
        __syncthreads();
        // GEMM2: X'^T = Y^T @ adj^T (B = adjB registers); X' -> sX[node][unit]
        {
            f32x4 acc[4][2];
            #pragma unroll
            for (int rt = 0; rt < 4; ++rt)
                #pragma unroll
                for (int ct = 0; ct < 2; ++ct) acc[rt][ct] = (f32x4){0.f,0.f,0.f,0.f};
            #pragma unroll
            for (int ks = 0; ks < 4; ++ks) {
                bf16x8 a0 = *(const bf16x8*)&sY[sidx(wm * 64 +  0 + c, ks * 32 + q * 8)];
                bf16x8 a1 = *(const bf16x8*)&sY[sidx(wm * 64 + 16 + c, ks * 32 + q * 8)];
                bf16x8 a2 = *(const bf16x8*)&sY[sidx(wm * 64 + 32 + c, ks * 32 + q * 8)];
                bf16x8 a3 = *(const bf16x8*)&sY[sidx(wm * 64 + 48 + c, ks * 32 + q * 8)];
                acc[0][0] = mfma16(a0, adjB[0][ks], acc[0][0]);
                acc[1][0] = mfma16(a1, adjB[0][ks], acc[1][0]);
                acc[2][0] = mfma16(a2, adjB[0][ks], acc[2][0]);
                acc[3][0] = mfma16(a3, adjB[0][ks], acc[3][0]);
                acc[0][1] = mfma16(a0, adjB[1][ks], acc[0][1]);
                acc[1][1] = mfma16(a1, adjB[1][ks], acc[1][1]);
                acc[2][1] = mfma16(a2, adjB[1][ks], acc[2][1]);
                acc[3][1] = mfma16(a3, adjB[1][ks], acc[3][1]);
            }
            #pragma unroll
            for (int ct = 0; ct < 2; ++ct) {
                int node = wn * 32 + ct * 16 + c;
                #pragma unroll
                for (int rt = 0; rt < 4; ++rt) {
                    int u0 = wm * 64 + rt * 16 + q * 4;  // 4 consecutive units
                    *(bf16x4*)&sX[sidx(node, u0)] = cvt4(acc[rt][ct]);
                }
            }
        }
        __syncthreads();
    }

    // ---- epilogue: masked mean pool + W_out dot ----
    {
        int node = tid >> 2, seg = tid & 3;
        float part = 0.f;
        #pragma unroll
        for (int t = 0; t < 4; ++t) {
            bf16x8 v = *(const bf16x8*)&sX[sidx(node, seg * 32 + t * 8)];
            const float* wo = W_out + seg * 32 + t * 8;
            #pragma unroll
            for (int j = 0; j < 8; ++j) part += (float)v[j] * wo[j];
        }
        float mv = mask[b * 128 + node];
        part *= mv;
        float msum = (seg == 0) ? mv : 0.f;
        #pragma unroll
        for (int off = 32; off > 0; off >>= 1) {
            part += __shfl_down(part, off);
            msum += __shfl_down(msum, off);
        }
        if (lane == 0) { red[wave] = part; red[8 + wave] = msum; }
        __syncthreads();
        if (tid == 0) {
            float s = 0.f, ms = 0.f;
            #pragma unroll
            for (int i = 0; i < 8; ++i) { s += red[i]; ms += red[8 + i]; }
            out[b] = s / fmaxf(ms, 1.f) + b_out[0];
        }
    }
}

extern "C" void kernel_launch(void* const* d_in, const int* in_sizes, int n_in,
                              void* d_out, int out_size, void* d_ws, size_t ws_size,
                              hipStream_t stream) {
    const int*   pdg   = (const int*)d_in[0];
    const float* feat  = (const float*)d_in[1];
    const float* adj   = (const float*)d_in[2];
    const float* mask  = (const float*)d_in[3];
    const float* emb   = (const float*)d_in[4];
    const float* W_in  = (const float*)d_in[5];
    const float* b_in  = (const float*)d_in[6];
    const float* W_h   = (const float*)d_in[7];
    const float* b_h   = (const float*)d_in[8];
    const float* W_out = (const float*)d_in[9];
    const float* b_out = (const float*)d_in[10];

    __bf16* wt_in = (__bf16*)d_ws;          // 128*32 bf16
    __bf16* wt_h  = wt_in + 4096;           // 6*128*128 bf16

    gcn_prep<<<400, 256, 0, stream>>>(W_in, W_h, wt_in, wt_h);
    gcn_main<<<4096, 512, 0, stream>>>(pdg, feat, adj, mask, emb, b_in, b_h,
                                       W_out, b_out, wt_in, wt_h, (float*)d_out);
}